// Round 2
// baseline (133.345 us; speedup 1.0000x reference)
//
#include <hip/hip_runtime.h>

#define BATCH   262144
#define FIN     128
#define FINP    129       // fan_in + 1 (bias col)
#define FOUT    128
#define NTILES  (BATCH / 16)   // 16384 row-tiles of 16

typedef __attribute__((ext_vector_type(8))) short short8;   // 8 bf16 (4 VGPR)
typedef __attribute__((ext_vector_type(4))) float f32x4;    // MFMA C/D

// f32 -> bf16, round-to-nearest-even
__device__ inline unsigned short f2bf(float f) {
    unsigned int u = __float_as_uint(f);
    return (unsigned short)((u + 0x7fffu + ((u >> 16) & 1u)) >> 16);
}

__global__ __launch_bounds__(256, 4)
void hashed_mfma(const float* __restrict__ a, const float* __restrict__ W,
                 const int* __restrict__ hidx, float* __restrict__ out) {
    // WbT[n][k] = W[hash_idx[n][k]] as bf16, row-major [128][128],
    // XOR-swizzled: byte_off ^= (n&7)<<4  -> conflict-free ds_read_b128.
    __shared__ __align__(16) unsigned char lds[32768 + 512];
    float* bias_lds = (float*)(lds + 32768);

    const int tid = threadIdx.x;

    // One-time per-block gather of the virtual weight matrix (W + hidx are
    // L1/L2-resident: 16 KB + 66 KB).
    for (int t = tid; t < FOUT * FIN; t += 256) {
        int n = t >> 7;          // fan_out index (GEMM col)
        int k = t & 127;         // fan_in index  (GEMM k)
        float v = W[hidx[n * FINP + k]];
        unsigned int off = (unsigned)(n * 256 + k * 2) ^ ((unsigned)(n & 7) << 4);
        *(unsigned short*)(lds + off) = f2bf(v);
    }
    if (tid < FOUT) bias_lds[tid] = W[hidx[tid * FINP + FIN]];  // bias col, kept fp32
    __syncthreads();

    const int wave = tid >> 6;
    const int lane = tid & 63;
    const int lr = lane & 15;   // A-row / B-col / C-col
    const int lk = lane >> 4;   // k-group (8 consecutive k per lane)

    const int NW = gridDim.x * 4;
    for (int tile = blockIdx.x * 4 + wave; tile < NTILES; tile += NW) {
        const float* arow = a + (size_t)tile * (16 * FIN);

        // Load 16x128 fp32 A-tile as MFMA fragments (8 consecutive k / lane), convert RNE.
        short8 af[4];
        #pragma unroll
        for (int kk = 0; kk < 4; ++kk) {
            const float* p = arow + lr * FIN + kk * 32 + lk * 8;
            float4 v0 = *reinterpret_cast<const float4*>(p);
            float4 v1 = *reinterpret_cast<const float4*>(p + 4);
            short8 s;
            s[0] = f2bf(v0.x); s[1] = f2bf(v0.y); s[2] = f2bf(v0.z); s[3] = f2bf(v0.w);
            s[4] = f2bf(v1.x); s[5] = f2bf(v1.y); s[6] = f2bf(v1.z); s[7] = f2bf(v1.w);
            af[kk] = s;
        }

        #pragma unroll
        for (int nt = 0; nt < 8; ++nt) {
            const int n = nt * 16 + lr;
            const float b = bias_lds[n];
            f32x4 acc = {b, b, b, b};   // bias column folded into C-init (exact fp32)
            #pragma unroll
            for (int kk = 0; kk < 4; ++kk) {
                unsigned int off = ((unsigned)(n * 256 + kk * 64 + lk * 16))
                                   ^ ((unsigned)(n & 7) << 4);
                short8 bfrag = *reinterpret_cast<const short8*>(lds + off);
                acc = __builtin_amdgcn_mfma_f32_16x16x32_bf16(af[kk], bfrag, acc, 0, 0, 0);
            }
            // C layout (m89): col = lane&15, row = (lane>>4)*4 + reg
            float* orow = out + (size_t)tile * (16 * FOUT) + (size_t)(lk * 4) * FOUT + n;
            orow[0]       = acc[0];
            orow[FOUT]    = acc[1];
            orow[2*FOUT]  = acc[2];
            orow[3*FOUT]  = acc[3];
        }
    }
}

extern "C" void kernel_launch(void* const* d_in, const int* in_sizes, int n_in,
                              void* d_out, int out_size, void* d_ws, size_t ws_size,
                              hipStream_t stream) {
    const float* a    = (const float*)d_in[0];
    const float* W    = (const float*)d_in[1];
    const int*   hidx = (const int*)d_in[2];
    float*       out  = (float*)d_out;

    // 1024 blocks = 4 blocks/CU (33 KB LDS each) * 256 CU -> exactly resident.
    hipLaunchKernelGGL(hashed_mfma, dim3(1024), dim3(256), 0, stream,
                       a, W, hidx, out);
}

// Round 3
// 123.824 us; speedup vs baseline: 1.0769x; 1.0769x over previous
//
#include <hip/hip_runtime.h>

#define BATCH   262144
#define FIN     128
#define FINP    129            // fan_in + 1 (bias col)
#define FOUT    128
#define NTILES  (BATCH / 16)   // 16384 row-tiles of 16

#define WMAT_BYTES 32768       // 128x128 bf16, swizzled
#define BIAS_OFF   32768       // then 128 f32 bias
#define WS_BYTES   33280

typedef __attribute__((ext_vector_type(8))) short short8;   // 8 bf16 (4 VGPR)
typedef __attribute__((ext_vector_type(4))) float f32x4;    // MFMA C/D

// f32 -> bf16, round-to-nearest-even
__device__ inline unsigned short f2bf(float f) {
    unsigned int u = __float_as_uint(f);
    return (unsigned short)((u + 0x7fffu + ((u >> 16) & 1u)) >> 16);
}

// --- Kernel 1: gather W[hash_idx] once into d_ws (swizzled bf16 Wmat + f32 bias) ---
__global__ __launch_bounds__(256)
void gather_w(const float* __restrict__ W, const int* __restrict__ hidx,
              unsigned char* __restrict__ ws) {
    int t = blockIdx.x * 256 + threadIdx.x;
    if (t < FOUT * FIN) {
        int n = t >> 7;        // fan_out (GEMM "M" after swap)
        int k = t & 127;
        float v = W[hidx[n * FINP + k]];
        unsigned int off = (unsigned)(n * 256 + k * 2) ^ ((unsigned)(n & 7) << 4);
        *(unsigned short*)(ws + off) = f2bf(v);
    } else if (t < FOUT * FIN + FOUT) {
        int n = t - FOUT * FIN;
        *(float*)(ws + BIAS_OFF + n * 4) = W[hidx[n * FINP + FIN]];  // bias, fp32 exact
    }
}

// --- Kernel 2: the GEMM. Stages Wmat from ws (L2-resident) into LDS, streams tiles. ---
__global__ __launch_bounds__(256, 4)
void hashed_mfma(const float* __restrict__ a, const unsigned char* __restrict__ ws,
                 float* __restrict__ out) {
    __shared__ __align__(16) unsigned char lds[WS_BYTES];

    const int tid = threadIdx.x;

    // Coalesced 33 KB copy: ws is L2-resident after the first few blocks.
    for (int t = tid; t < WS_BYTES / 16; t += 256)
        *reinterpret_cast<f32x4*>(lds + t * 16) =
            *reinterpret_cast<const f32x4*>(ws + t * 16);
    __syncthreads();

    const int wave = tid >> 6;
    const int lane = tid & 63;
    const int lr = lane & 15;   // out-row-within-tile (B-operand col) / W row (A-operand row)
    const int lk = lane >> 4;   // k-group (8 consecutive k per lane)

    // Bias hoisted to registers: lane's 4 output cols per nt are nt*16 + lk*4 .. +3.
    f32x4 biasv[8];
    #pragma unroll
    for (int nt = 0; nt < 8; ++nt)
        biasv[nt] = *reinterpret_cast<const f32x4*>(lds + BIAS_OFF + nt * 64 + lk * 16);

    const int NW = gridDim.x * 4;
    for (int tile = blockIdx.x * 4 + wave; tile < NTILES; tile += NW) {
        const float* arow = a + (size_t)tile * (16 * FIN);

        // 16x128 fp32 A-tile -> bf16 MFMA B-operand frags (col = lr, 8 consecutive k).
        short8 af[4];
        #pragma unroll
        for (int kk = 0; kk < 4; ++kk) {
            const float* p = arow + lr * FIN + kk * 32 + lk * 8;
            float4 v0 = *reinterpret_cast<const float4*>(p);
            float4 v1 = *reinterpret_cast<const float4*>(p + 4);
            short8 s;
            s[0] = f2bf(v0.x); s[1] = f2bf(v0.y); s[2] = f2bf(v0.z); s[3] = f2bf(v0.w);
            s[4] = f2bf(v1.x); s[5] = f2bf(v1.y); s[6] = f2bf(v1.z); s[7] = f2bf(v1.w);
            af[kk] = s;
        }

        #pragma unroll
        for (int nt = 0; nt < 8; ++nt) {
            const int n = nt * 16 + lr;           // W row for this lane's A-operand frag
            f32x4 acc = biasv[nt];
            #pragma unroll
            for (int kk = 0; kk < 4; ++kk) {
                unsigned int off = ((unsigned)(n * 256 + kk * 64 + lk * 16))
                                   ^ ((unsigned)(n & 7) << 4);
                short8 wfrag = *reinterpret_cast<const short8*>(lds + off);
                // D = W · a^T : D row = out-col (n), D col = out-row (b).
                acc = __builtin_amdgcn_mfma_f32_16x16x32_bf16(wfrag, af[kk], acc, 0, 0, 0);
            }
            // Lane holds out[tile*16 + lr][nt*16 + lk*4 .. +3] -> one dwordx4 store.
            *reinterpret_cast<f32x4*>(out + (size_t)(tile * 16 + lr) * FOUT
                                          + nt * 16 + lk * 4) = acc;
        }
    }
}

extern "C" void kernel_launch(void* const* d_in, const int* in_sizes, int n_in,
                              void* d_out, int out_size, void* d_ws, size_t ws_size,
                              hipStream_t stream) {
    const float* a    = (const float*)d_in[0];
    const float* W    = (const float*)d_in[1];
    const int*   hidx = (const int*)d_in[2];
    float*       out  = (float*)d_out;
    unsigned char* ws = (unsigned char*)d_ws;

    hipLaunchKernelGGL(gather_w, dim3((FOUT * FINP + 255) / 256), dim3(256), 0, stream,
                       W, hidx, ws);
    hipLaunchKernelGGL(hashed_mfma, dim3(1024), dim3(256), 0, stream,
                       a, ws, out);
}